// Round 1
// baseline (1541.669 us; speedup 1.0000x reference)
//
#include <hip/hip_runtime.h>
#include <hip/hip_bf16.h>
#include <cstdint>

// Problem dims (fixed by reference): B=4, S=2048 -> M=8192, K=4096, N=16384
#define MDIM 8192
#define KDIM 4096
#define NDIM 16384

typedef int v4i __attribute__((ext_vector_type(4)));

__device__ __forceinline__ void gload_lds16(const void* g, void* l) {
    __builtin_amdgcn_global_load_lds(
        (const __attribute__((address_space(1))) int*)g,
        (__attribute__((address_space(3))) int*)l, 16, 0, 0);
}

// ---------------------------------------------------------------------------
// Kernel 1: pack W int32 [N,K] -> int8 [N,K]. One int4 (4 ints) -> one int (4 bytes).
__global__ __launch_bounds__(256) void conv_w(const int4* __restrict__ w,
                                              int* __restrict__ wq) {
    int g = blockIdx.x * 256 + threadIdx.x;   // int4 index; total N*K/4 = 16777216
    int4 v = w[g];
    unsigned p = (unsigned)(v.x & 255) | ((unsigned)(v.y & 255) << 8) |
                 ((unsigned)(v.z & 255) << 16) | ((unsigned)(v.w & 255) << 24);
    wq[g] = (int)p;
}

// ---------------------------------------------------------------------------
// Kernel 2: per-row absmax quantize of x [M,K] fp32 -> int8 + scale_x[M].
// One block per row. 256 threads * 16 floats = 4096 = K.
__global__ __launch_bounds__(256) void quant_rows(const float* __restrict__ x,
                                                  int* __restrict__ xq32,
                                                  float* __restrict__ sx) {
    const int row = blockIdx.x;
    const int t = threadIdx.x;
    const float4* xr = (const float4*)(x + (size_t)row * KDIM);

    float4 v[4];
    float amax = 0.f;
#pragma unroll
    for (int p = 0; p < 4; ++p) {
        v[p] = xr[p * 256 + t];
        amax = fmaxf(amax, fmaxf(fmaxf(fabsf(v[p].x), fabsf(v[p].y)),
                                 fmaxf(fabsf(v[p].z), fabsf(v[p].w))));
    }
    // wave64 reduce
#pragma unroll
    for (int off = 32; off > 0; off >>= 1)
        amax = fmaxf(amax, __shfl_down(amax, off));
    __shared__ float wmax[4];
    int wave = t >> 6, lane = t & 63;
    if (lane == 0) wmax[wave] = amax;
    __syncthreads();
    float m = fmaxf(fmaxf(wmax[0], wmax[1]), fmaxf(wmax[2], wmax[3]));

    float inv = (m > 0.f) ? 127.f / m : 0.f;
    if (t == 0) {
        float s = m / 127.f;
        sx[row] = (s == 0.f) ? 1.f : s;
    }

    int* out = xq32 + (size_t)row * (KDIM / 4);
#pragma unroll
    for (int p = 0; p < 4; ++p) {
        int q0 = (int)rintf(v[p].x * inv); q0 = max(-127, min(127, q0));
        int q1 = (int)rintf(v[p].y * inv); q1 = max(-127, min(127, q1));
        int q2 = (int)rintf(v[p].z * inv); q2 = max(-127, min(127, q2));
        int q3 = (int)rintf(v[p].w * inv); q3 = max(-127, min(127, q3));
        unsigned pk = (unsigned)(q0 & 255) | ((unsigned)(q1 & 255) << 8) |
                      ((unsigned)(q2 & 255) << 16) | ((unsigned)(q3 & 255) << 24);
        out[p * 256 + t] = (int)pk;
    }
}

// ---------------------------------------------------------------------------
// Kernel 3: int8 GEMM, C[m][n] = sum_k xq[m][k]*wq[n][k], fused scale/bias epilogue.
// 128x128 tile per block (256 thr / 4 waves, each wave 64x64), BK=64,
// global_load_lds width-16 staging, mfma_i32_16x16x64_i8.
__global__ __launch_bounds__(256) void gemm_i8(const signed char* __restrict__ xq,
                                               const signed char* __restrict__ wq,
                                               const float* __restrict__ sx,
                                               const float* __restrict__ scale,
                                               const float* __restrict__ bias,
                                               float* __restrict__ y) {
    __shared__ __align__(16) signed char lds_a[128 * 64];
    __shared__ __align__(16) signed char lds_b[128 * 64];

    const int tid = threadIdx.x;
    const int wave = tid >> 6, lane = tid & 63;
    const int quad = lane >> 4, l16 = lane & 15;
    const int tileM = blockIdx.y * 128, tileN = blockIdx.x * 128;
    const int wm = (wave >> 1) * 64, wn = (wave & 1) * 64;

    const signed char* ga = xq + (size_t)tileM * KDIM;
    const signed char* gb = wq + (size_t)tileN * KDIM;

    v4i acc[4][4] = {};

    for (int k0 = 0; k0 < KDIM; k0 += 64) {
        __syncthreads();   // prior iter's ds_reads done before LDS overwrite
#pragma unroll
        for (int p = 0; p < 2; ++p) {
            int off = (p * 4 + wave) * 1024 + lane * 16;  // byte offset in 8KB tile
            int mr = off >> 6;       // row within 128
            int kb = off & 63;       // byte within 64-byte K-run
            gload_lds16(ga + (size_t)mr * KDIM + k0 + kb, lds_a + off);
            gload_lds16(gb + (size_t)mr * KDIM + k0 + kb, lds_b + off);
        }
        __syncthreads();   // staging visible (compiler drains vmcnt before barrier)

        v4i af[4], bf[4];
#pragma unroll
        for (int i = 0; i < 4; ++i) {
            af[i] = *(const v4i*)(lds_a + (wm + i * 16 + l16) * 64 + quad * 16);
            bf[i] = *(const v4i*)(lds_b + (wn + i * 16 + l16) * 64 + quad * 16);
        }
#pragma unroll
        for (int i = 0; i < 4; ++i)
#pragma unroll
            for (int j = 0; j < 4; ++j)
                acc[i][j] = __builtin_amdgcn_mfma_i32_16x16x64_i8(af[i], bf[j],
                                                                  acc[i][j], 0, 0, 0);
    }

    // Epilogue: C/D layout col=lane&15, row=quad*4+reg (shape-determined, m121/m128)
#pragma unroll
    for (int j = 0; j < 4; ++j) {
        int n = tileN + wn + j * 16 + l16;
        float scn = scale[n];
        float bsn = bias[n];
#pragma unroll
        for (int i = 0; i < 4; ++i) {
#pragma unroll
            for (int r = 0; r < 4; ++r) {
                int m = tileM + wm + i * 16 + quad * 4 + r;
                y[(size_t)m * NDIM + n] =
                    (float)acc[i][j][r] * sx[m] * scn + bsn;
            }
        }
    }
}

// ---------------------------------------------------------------------------
extern "C" void kernel_launch(void* const* d_in, const int* in_sizes, int n_in,
                              void* d_out, int out_size, void* d_ws, size_t ws_size,
                              hipStream_t stream) {
    const float* x      = (const float*)d_in[0];   // [4,2048,4096] f32
    const int*   wdat   = (const int*)d_in[1];     // [16384,4096] int32 (int8 range)
    const float* scale  = (const float*)d_in[2];   // [16384,1]
    const float* bias   = (const float*)d_in[3];   // [16384]
    float* y = (float*)d_out;                      // [4,2048,16384] f32

    signed char* wq = (signed char*)d_ws;                       // N*K   = 64 MiB
    signed char* xq = wq + (size_t)NDIM * KDIM;                 // M*K   = 32 MiB
    float*       sx = (float*)(xq + (size_t)MDIM * KDIM);       // M*4   = 32 KiB

    conv_w<<<(NDIM * (size_t)KDIM) / 4 / 256, 256, 0, stream>>>((const int4*)wdat,
                                                                (int*)wq);
    quant_rows<<<MDIM, 256, 0, stream>>>(x, (int*)xq, sx);

    dim3 grid(NDIM / 128, MDIM / 128);   // (128, 64)
    gemm_i8<<<grid, 256, 0, stream>>>(xq, wq, sx, scale, bias, y);
}